// Round 9
// baseline (424.566 us; speedup 1.0000x reference)
//
#include <hip/hip_runtime.h>

// ---------------- problem constants ----------------
#define CCH   256
#define HH    96
#define WW    96
#define HO    94
#define LL    8836        // 94*94 patches
#define DD    2304        // 256*9 bytes per patch row (i8)
#define LPAD  8960        // 35 * 256

// GEMM: 256x256 tile, 8 waves (2M x 4N), 512 threads, i8 16x16x64 MFMA.
// K in 36 slices of 64 B/row; LDS ring-2 slots of (A 16KB + B 16KB) = 64 KiB.
#define BM2   256
#define NT2   35          // 8960/256
#define NPH   36          // 2304/64
#define SLOTB 32768       // bytes per ring slot
#define ROWS2 294912      // 128 * 2304 (second row-half offset)

typedef unsigned char u8;
typedef unsigned long long u64;

using i32x4 = __attribute__((ext_vector_type(4))) int;

// ---------------- workspace layout (bytes) ----------------
#define OFF_BQ    20643840ull
#define OFF_RNB   41287680ull
#define OFF_N2B   41323520ull
#define OFF_W2X   41359360ull
#define OFF_QSA   41395200ull
#define OFF_QSB   41431040ull
#define OFF_COLS  41466880ull
#define OFF_SAF   41502720ull
#define OFF_P2    41538560ull
#define OFF_PM    41612288ull
#define OFF_BEST  41686016ull

__device__ __forceinline__ void gload16(const void* g, void* l) {
    __builtin_amdgcn_global_load_lds(
        (const __attribute__((address_space(1))) unsigned int*)g,
        (__attribute__((address_space(3))) unsigned int*)l,
        16, 0, 0);
}

// ---- 1: per-pixel channel sum-of-squares and abs-max for both images ----
__global__ __launch_bounds__(256) void k_chan_stats(const float* __restrict__ st,
                                                    const float* __restrict__ x,
                                                    float* __restrict__ P2,
                                                    float* __restrict__ PM) {
    int p = blockIdx.x * 256 + threadIdx.x;
    if (p >= 2 * HH * WW) return;
    const float* img = (p < HH * WW) ? st : x;
    int pp = (p < HH * WW) ? p : p - HH * WW;
    float s = 0.f, m = 0.f;
#pragma unroll 4
    for (int c = 0; c < CCH; ++c) {
        float v = img[c * (HH * WW) + pp];
        s += v * v;
        m = fmaxf(m, fabsf(v));
    }
    P2[p] = s;
    PM[p] = m;
}

// ---- 2: 3x3 window reductions -> norms and quantizer scales ----
__global__ __launch_bounds__(256) void k_win(const float* __restrict__ P2,
                                             const float* __restrict__ PM,
                                             float* __restrict__ rnB,
                                             float* __restrict__ n2B,
                                             float* __restrict__ win2x,
                                             float* __restrict__ qsA,
                                             float* __restrict__ qsB,
                                             float* __restrict__ colS,
                                             float* __restrict__ sAf) {
    int i = blockIdx.x * 256 + threadIdx.x;
    if (i >= LL) return;
    int y = i / HO, xc = i % HO;
    float ss = 0.f, sx = 0.f, ms = 0.f, mx = 0.f;
#pragma unroll
    for (int kh = 0; kh < 3; ++kh)
#pragma unroll
        for (int kw = 0; kw < 3; ++kw) {
            int off = (y + kh) * WW + xc + kw;
            ss += P2[off];
            sx += P2[HH * WW + off];
            ms = fmaxf(ms, PM[off]);
            mx = fmaxf(mx, PM[HH * WW + off]);
        }
    float rn = 1.f / (sqrtf(ss) + 1e-8f);
    float msc = fmaxf(ms, 1e-30f), mxc = fmaxf(mx, 1e-30f);
    rnB[i] = rn;
    n2B[i] = ss;
    win2x[i] = sx;
    qsA[i] = 127.f / mxc;
    qsB[i] = 127.f / msc;
    colS[i] = rn * msc * (1.f / 127.f);
    sAf[i] = mxc * (1.f / 127.f);
}

// ---- 3: quantize patches to i8 [LPAD][2304] ----
__global__ __launch_bounds__(256) void k_pack(const float* __restrict__ x,
                                              const float* __restrict__ st,
                                              const float* __restrict__ qsA,
                                              const float* __restrict__ qsB,
                                              u8* __restrict__ Aq,
                                              u8* __restrict__ Bq) {
    int row = blockIdx.x;
    bool isB = row >= LPAD;
    int i = isB ? row - LPAD : row;
    u8* dst = (isB ? Bq : Aq) + (size_t)i * DD + threadIdx.x * 9;
    if (i >= LL) {
#pragma unroll
        for (int k = 0; k < 9; ++k) dst[k] = 0;
        return;
    }
    int y = i / HO, xc = i % HO;
    const float* src = isB ? st : x;
    float scale = isB ? qsB[i] : qsA[i];
    const float* base = src + (size_t)threadIdx.x * (HH * WW) + y * WW + xc;
#pragma unroll
    for (int kh = 0; kh < 3; ++kh)
#pragma unroll
        for (int kw = 0; kw < 3; ++kw) {
            int q = (int)rintf(base[kh * WW + kw] * scale);
            dst[kh * 3 + kw] = (u8)q;
        }
}

// ---- 4: fused i8 GEMM (A * B^T) + per-row scaled argmax, lean ring-2 body ----
__global__ __launch_bounds__(512, 2) void k_gemm2(const u8* __restrict__ A,
                                                  const u8* __restrict__ Bm,
                                                  const float* __restrict__ colS,
                                                  u64* __restrict__ best) {
    extern __shared__ __align__(16) u8 lds[];  // 2 x 32 KB = 64 KiB

    const int t = threadIdx.x;
    const int wid = t >> 6, lane = t & 63;
    const int wr = wid >> 2, wc = wid & 3;
    const int l15 = lane & 15, l4 = lane >> 4;

    // T1: bijective XCD swizzle (m204), nwg = 1225
    const int nwg = NT2 * NT2;
    const int q = nwg >> 3, r = nwg & 7;  // 153, 1
    const int bid = blockIdx.x;
    const int xcd = bid & 7, loc = bid >> 3;
    const int swz = ((xcd < r) ? xcd * (q + 1) : r * (q + 1) + (xcd - r) * q) + loc;
    const int it = swz / NT2, jt = swz % NT2;

    // staging: uniform block base (SGPR) + loop-invariant lane offset (VGPR)
    const int gsrc = (t & 3) ^ ((t >> 3) & 3);   // pre-swizzled 16B k-group
    const int laneG = (t >> 2) * DD + gsrc * 16; // per-lane, loop-invariant
    const u8* pAblk = A  + (size_t)(it * BM2) * DD;
    const u8* pBblk = Bm + (size_t)(jt * BM2) * DD;
    u8* ldsT = lds + t * 16;                     // per-lane LDS stage dest

    // fragment read offsets (swizzled): phys 16B-group = l4 ^ ((row>>1)&3)
    const int sp16 = (l4 ^ ((l15 >> 1) & 3)) * 16;
    int aoff[8], boff[4];
#pragma unroll
    for (int mi = 0; mi < 8; ++mi)
        aoff[mi] = (wr * 128 + mi * 16 + l15) * 64 + sp16;
#pragma unroll
    for (int ni = 0; ni < 4; ++ni)
        boff[ni] = 16384 + (wc * 64 + ni * 16 + l15) * 64 + sp16;

    i32x4 acc[8][4];
#pragma unroll
    for (int mi = 0; mi < 8; ++mi)
#pragma unroll
        for (int ni = 0; ni < 4; ++ni)
            acc[mi][ni] = (i32x4){0, 0, 0, 0};

    // prologue: stage slice 0 into slot 0
    gload16(pAblk + laneG,          ldsT);
    gload16(pAblk + laneG + ROWS2,  ldsT + 8192);
    gload16(pBblk + laneG,          ldsT + 16384);
    gload16(pBblk + laneG + ROWS2,  ldsT + 24576);

// BODY(SL): slot SL holds slice s; stage slice s+1 into slot 1-SL;
// 2 barriers, vmcnt(4), split lgkm for read/MFMA overlap.
#define BODY(SREL, SL)                                                       \
    {                                                                        \
        const u8* pAs = pAblk + (size_t)(s4 + (SREL) + 1) * 64;              \
        const u8* pBs = pBblk + (size_t)(s4 + (SREL) + 1) * 64;              \
        u8* d = ldsT + (1 - (SL)) * SLOTB;                                   \
        gload16(pAs + laneG,         d);                                     \
        gload16(pAs + laneG + ROWS2, d + 8192);                              \
        gload16(pBs + laneG,         d + 16384);                             \
        gload16(pBs + laneG + ROWS2, d + 24576);                             \
        asm volatile("s_waitcnt vmcnt(4)" ::: "memory");                     \
        __builtin_amdgcn_sched_barrier(0);                                   \
        __builtin_amdgcn_s_barrier();                                        \
        i32x4 af0, af1, af2, af3, af4, af5, af6, af7, bf0, bf1, bf2, bf3;    \
        af0 = *(const i32x4*)(lds + (SL) * SLOTB + aoff[0]);                 \
        af1 = *(const i32x4*)(lds + (SL) * SLOTB + aoff[1]);                 \
        bf0 = *(const i32x4*)(lds + (SL) * SLOTB + boff[0]);                 \
        bf1 = *(const i32x4*)(lds + (SL) * SLOTB + boff[1]);                 \
        bf2 = *(const i32x4*)(lds + (SL) * SLOTB + boff[2]);                 \
        bf3 = *(const i32x4*)(lds + (SL) * SLOTB + boff[3]);                 \
        __builtin_amdgcn_sched_barrier(0);                                   \
        af2 = *(const i32x4*)(lds + (SL) * SLOTB + aoff[2]);                 \
        af3 = *(const i32x4*)(lds + (SL) * SLOTB + aoff[3]);                 \
        af4 = *(const i32x4*)(lds + (SL) * SLOTB + aoff[4]);                 \
        af5 = *(const i32x4*)(lds + (SL) * SLOTB + aoff[5]);                 \
        af6 = *(const i32x4*)(lds + (SL) * SLOTB + aoff[6]);                 \
        af7 = *(const i32x4*)(lds + (SL) * SLOTB + aoff[7]);                 \
        asm volatile("s_waitcnt lgkmcnt(6)" ::: "memory");                   \
        __builtin_amdgcn_sched_barrier(0);                                   \
        __builtin_amdgcn_s_setprio(1);                                       \
        acc[0][0] = __builtin_amdgcn_mfma_i32_16x16x64_i8(af0, bf0, acc[0][0], 0, 0, 0); \
        acc[0][1] = __builtin_amdgcn_mfma_i32_16x16x64_i8(af0, bf1, acc[0][1], 0, 0, 0); \
        acc[0][2] = __builtin_amdgcn_mfma_i32_16x16x64_i8(af0, bf2, acc[0][2], 0, 0, 0); \
        acc[0][3] = __builtin_amdgcn_mfma_i32_16x16x64_i8(af0, bf3, acc[0][3], 0, 0, 0); \
        acc[1][0] = __builtin_amdgcn_mfma_i32_16x16x64_i8(af1, bf0, acc[1][0], 0, 0, 0); \
        acc[1][1] = __builtin_amdgcn_mfma_i32_16x16x64_i8(af1, bf1, acc[1][1], 0, 0, 0); \
        acc[1][2] = __builtin_amdgcn_mfma_i32_16x16x64_i8(af1, bf2, acc[1][2], 0, 0, 0); \
        acc[1][3] = __builtin_amdgcn_mfma_i32_16x16x64_i8(af1, bf3, acc[1][3], 0, 0, 0); \
        asm volatile("s_waitcnt lgkmcnt(0)" ::: "memory");                   \
        __builtin_amdgcn_sched_barrier(0);                                   \
        acc[2][0] = __builtin_amdgcn_mfma_i32_16x16x64_i8(af2, bf0, acc[2][0], 0, 0, 0); \
        acc[2][1] = __builtin_amdgcn_mfma_i32_16x16x64_i8(af2, bf1, acc[2][1], 0, 0, 0); \
        acc[2][2] = __builtin_amdgcn_mfma_i32_16x16x64_i8(af2, bf2, acc[2][2], 0, 0, 0); \
        acc[2][3] = __builtin_amdgcn_mfma_i32_16x16x64_i8(af2, bf3, acc[2][3], 0, 0, 0); \
        acc[3][0] = __builtin_amdgcn_mfma_i32_16x16x64_i8(af3, bf0, acc[3][0], 0, 0, 0); \
        acc[3][1] = __builtin_amdgcn_mfma_i32_16x16x64_i8(af3, bf1, acc[3][1], 0, 0, 0); \
        acc[3][2] = __builtin_amdgcn_mfma_i32_16x16x64_i8(af3, bf2, acc[3][2], 0, 0, 0); \
        acc[3][3] = __builtin_amdgcn_mfma_i32_16x16x64_i8(af3, bf3, acc[3][3], 0, 0, 0); \
        acc[4][0] = __builtin_amdgcn_mfma_i32_16x16x64_i8(af4, bf0, acc[4][0], 0, 0, 0); \
        acc[4][1] = __builtin_amdgcn_mfma_i32_16x16x64_i8(af4, bf1, acc[4][1], 0, 0, 0); \
        acc[4][2] = __builtin_amdgcn_mfma_i32_16x16x64_i8(af4, bf2, acc[4][2], 0, 0, 0); \
        acc[4][3] = __builtin_amdgcn_mfma_i32_16x16x64_i8(af4, bf3, acc[4][3], 0, 0, 0); \
        acc[5][0] = __builtin_amdgcn_mfma_i32_16x16x64_i8(af5, bf0, acc[5][0], 0, 0, 0); \
        acc[5][1] = __builtin_amdgcn_mfma_i32_16x16x64_i8(af5, bf1, acc[5][1], 0, 0, 0); \
        acc[5][2] = __builtin_amdgcn_mfma_i32_16x16x64_i8(af5, bf2, acc[5][2], 0, 0, 0); \
        acc[5][3] = __builtin_amdgcn_mfma_i32_16x16x64_i8(af5, bf3, acc[5][3], 0, 0, 0); \
        acc[6][0] = __builtin_amdgcn_mfma_i32_16x16x64_i8(af6, bf0, acc[6][0], 0, 0, 0); \
        acc[6][1] = __builtin_amdgcn_mfma_i32_16x16x64_i8(af6, bf1, acc[6][1], 0, 0, 0); \
        acc[6][2] = __builtin_amdgcn_mfma_i32_16x16x64_i8(af6, bf2, acc[6][2], 0, 0, 0); \
        acc[6][3] = __builtin_amdgcn_mfma_i32_16x16x64_i8(af6, bf3, acc[6][3], 0, 0, 0); \
        acc[7][0] = __builtin_amdgcn_mfma_i32_16x16x64_i8(af7, bf0, acc[7][0], 0, 0, 0); \
        acc[7][1] = __builtin_amdgcn_mfma_i32_16x16x64_i8(af7, bf1, acc[7][1], 0, 0, 0); \
        acc[7][2] = __builtin_amdgcn_mfma_i32_16x16x64_i8(af7, bf2, acc[7][2], 0, 0, 0); \
        acc[7][3] = __builtin_amdgcn_mfma_i32_16x16x64_i8(af7, bf3, acc[7][3], 0, 0, 0); \
        __builtin_amdgcn_s_setprio(0);                                       \
        __builtin_amdgcn_s_barrier();                                        \
    }

    for (int s4 = 0; s4 < NPH; s4 += 2) {
        BODY(0, 0)
        BODY(1, 1)
    }
#undef BODY

    // epilogue: per output row, argmax of (int dot * colS_j) over 256 j's
    const int jbase = jt * BM2 + wc * 64 + l15;
    float cs[4];
#pragma unroll
    for (int ni = 0; ni < 4; ++ni) {
        int j = jbase + ni * 16;
        cs[ni] = colS[j < LL ? j : 0];
    }
#pragma unroll
    for (int mi = 0; mi < 8; ++mi) {
#pragma unroll
        for (int rr = 0; rr < 4; ++rr) {
            float bv = -3.4e38f;
            int bj = 0x7FFFFFFF;
#pragma unroll
            for (int ni = 0; ni < 4; ++ni) {
                int j = jbase + ni * 16;
                float v = (float)acc[mi][ni][rr] * cs[ni];
                if (j < LL && (v > bv || (v == bv && j < bj))) { bv = v; bj = j; }
            }
#pragma unroll
            for (int m = 1; m < 16; m <<= 1) {
                float ov = __shfl_xor(bv, m, 64);
                int oj = __shfl_xor(bj, m, 64);
                if (ov > bv || (ov == bv && oj < bj)) { bv = ov; bj = oj; }
            }
            if (l15 == 0) {
                int i = it * BM2 + wr * 128 + mi * 16 + l4 * 4 + rr;
                if (i < LL) {
                    unsigned u = __float_as_uint(bv);
                    unsigned s = (bv < 0.f) ? ~u : (u | 0x80000000u);
                    u64 packed = ((u64)s << 32) | (unsigned)(~(unsigned)bj);
                    atomicMax(&best[i], packed);
                }
            }
        }
    }
}

// ---- 5: final scalar ----
__global__ __launch_bounds__(256) void k_final(const u64* __restrict__ best,
                                               const float* __restrict__ rnB,
                                               const float* __restrict__ n2B,
                                               const float* __restrict__ win2x,
                                               const float* __restrict__ sAf,
                                               float* __restrict__ out) {
    int i = blockIdx.x * 256 + threadIdx.x;
    float contrib = 0.f;
    if (i < LL) {
        u64 p = best[i];
        unsigned s = (unsigned)(p >> 32);
        unsigned ub = (s & 0x80000000u) ? (s & 0x7FFFFFFFu) : ~s;
        float bv = __uint_as_float(ub);
        int j = (int)(~(unsigned)(p & 0xFFFFFFFFull));
        float dot = (bv * sAf[i]) / rnB[j];
        contrib = win2x[i] + n2B[j] - 2.f * dot;
    }
    float sred = contrib;
#pragma unroll
    for (int o = 32; o > 0; o >>= 1) sred += __shfl_down(sred, o, 64);
    __shared__ float red[4];
    if ((threadIdx.x & 63) == 0) red[threadIdx.x >> 6] = sred;
    __syncthreads();
    if (threadIdx.x == 0) {
        float tot = red[0] + red[1] + red[2] + red[3];
        atomicAdd(out, tot * (1.0f / ((float)DD * (float)LL)));
    }
}

extern "C" void kernel_launch(void* const* d_in, const int* in_sizes, int n_in,
                              void* d_out, int out_size, void* d_ws, size_t ws_size,
                              hipStream_t stream) {
    const float* x  = (const float*)d_in[0];
    const float* st = (const float*)d_in[1];
    char* ws = (char*)d_ws;

    u8* Aq       = (u8*)ws;
    u8* Bq       = (u8*)(ws + OFF_BQ);
    float* rnB   = (float*)(ws + OFF_RNB);
    float* n2B   = (float*)(ws + OFF_N2B);
    float* win2x = (float*)(ws + OFF_W2X);
    float* qsA   = (float*)(ws + OFF_QSA);
    float* qsB   = (float*)(ws + OFF_QSB);
    float* colS  = (float*)(ws + OFF_COLS);
    float* sAf   = (float*)(ws + OFF_SAF);
    float* P2    = (float*)(ws + OFF_P2);
    float* PM    = (float*)(ws + OFF_PM);
    u64* best    = (u64*)(ws + OFF_BEST);
    float* out   = (float*)d_out;

    hipFuncSetAttribute((const void*)k_gemm2,
                        hipFuncAttributeMaxDynamicSharedMemorySize, 65536);

    hipMemsetAsync(best, 0, (size_t)LL * 8, stream);
    hipMemsetAsync(out, 0, sizeof(float), stream);

    k_chan_stats<<<dim3(72), dim3(256), 0, stream>>>(st, x, P2, PM);
    k_win<<<dim3(35), dim3(256), 0, stream>>>(P2, PM, rnB, n2B, win2x, qsA, qsB, colS, sAf);
    k_pack<<<dim3(2 * LPAD), dim3(256), 0, stream>>>(x, st, qsA, qsB, Aq, Bq);
    k_gemm2<<<dim3(NT2 * NT2), dim3(512), 65536, stream>>>(Aq, Bq, colS, best);
    k_final<<<dim3(35), dim3(256), 0, stream>>>(best, rnB, n2B, win2x, sAf, out);
}

// Round 10
// 399.957 us; speedup vs baseline: 1.0615x; 1.0615x over previous
//
#include <hip/hip_runtime.h>

// ---------------- problem constants ----------------
#define CCH   256
#define HH    96
#define WW    96
#define HO    94
#define LL    8836        // 94*94 patches
#define DD    2304        // 256*9 bytes per patch row (i8)
#define LPAD  8960        // 35 * 256

// GEMM geometry: 256x256 tile, 8 waves (2M x 4N), 512 threads, i8 K=64 MFMA.
// K in 36 slices of 64 (64 B per row per slice); LDS ring of 4 (A+B) slices.
#define BM2   256
#define NT2   35          // 8960/256
#define NPH   36          // 2304/64
#define ASLB  16384       // bytes per slice (256 rows x 64 B)
#define BBASEB 65536      // B slices start (bytes)

typedef unsigned char u8;
typedef unsigned long long u64;

using i32x4 = __attribute__((ext_vector_type(4))) int;

// ---------------- workspace layout (bytes) ----------------
#define OFF_BQ    20643840ull
#define OFF_RNB   41287680ull
#define OFF_N2B   41323520ull
#define OFF_W2X   41359360ull
#define OFF_QSA   41395200ull
#define OFF_QSB   41431040ull
#define OFF_COLS  41466880ull
#define OFF_SAF   41502720ull
#define OFF_P2    41538560ull
#define OFF_PM    41612288ull
#define OFF_BEST  41686016ull

__device__ __forceinline__ void gload16(const void* g, void* l) {
    __builtin_amdgcn_global_load_lds(
        (const __attribute__((address_space(1))) unsigned int*)g,
        (__attribute__((address_space(3))) unsigned int*)l,
        16, 0, 0);
}

// ---- 1: per-pixel channel sum-of-squares and abs-max for both images ----
__global__ __launch_bounds__(256) void k_chan_stats(const float* __restrict__ st,
                                                    const float* __restrict__ x,
                                                    float* __restrict__ P2,
                                                    float* __restrict__ PM) {
    int p = blockIdx.x * 256 + threadIdx.x;
    if (p >= 2 * HH * WW) return;
    const float* img = (p < HH * WW) ? st : x;
    int pp = (p < HH * WW) ? p : p - HH * WW;
    float s = 0.f, m = 0.f;
#pragma unroll 4
    for (int c = 0; c < CCH; ++c) {
        float v = img[c * (HH * WW) + pp];
        s += v * v;
        m = fmaxf(m, fabsf(v));
    }
    P2[p] = s;
    PM[p] = m;
}

// ---- 2: 3x3 window reductions -> norms and quantizer scales ----
__global__ __launch_bounds__(256) void k_win(const float* __restrict__ P2,
                                             const float* __restrict__ PM,
                                             float* __restrict__ rnB,
                                             float* __restrict__ n2B,
                                             float* __restrict__ win2x,
                                             float* __restrict__ qsA,
                                             float* __restrict__ qsB,
                                             float* __restrict__ colS,
                                             float* __restrict__ sAf) {
    int i = blockIdx.x * 256 + threadIdx.x;
    if (i >= LL) return;
    int y = i / HO, xc = i % HO;
    float ss = 0.f, sx = 0.f, ms = 0.f, mx = 0.f;
#pragma unroll
    for (int kh = 0; kh < 3; ++kh)
#pragma unroll
        for (int kw = 0; kw < 3; ++kw) {
            int off = (y + kh) * WW + xc + kw;
            ss += P2[off];
            sx += P2[HH * WW + off];
            ms = fmaxf(ms, PM[off]);
            mx = fmaxf(mx, PM[HH * WW + off]);
        }
    float rn = 1.f / (sqrtf(ss) + 1e-8f);
    float msc = fmaxf(ms, 1e-30f), mxc = fmaxf(mx, 1e-30f);
    rnB[i] = rn;
    n2B[i] = ss;
    win2x[i] = sx;
    qsA[i] = 127.f / mxc;
    qsB[i] = 127.f / msc;
    colS[i] = rn * msc * (1.f / 127.f);
    sAf[i] = mxc * (1.f / 127.f);
}

// ---- 3: quantize patches to i8, LDS-transposed for coalesced output ----
// block = (y, half, side): 47 patch rows; t -> (i_local, kh, kw); loop channels;
// bytes land in LDS [47][2304], then one contiguous coalesced 108 KB store.
__global__ __launch_bounds__(512) void k_pack(const float* __restrict__ x,
                                              const float* __restrict__ st,
                                              const float* __restrict__ qsA,
                                              const float* __restrict__ qsB,
                                              u8* __restrict__ Aq,
                                              u8* __restrict__ Bq) {
    extern __shared__ u8 plds[];   // 47 * 2304 = 108288 bytes

    const int b = blockIdx.x;
    const int side = b & 1;            // 0 = A (x), 1 = B (style)
    const int half = (b >> 1) & 1;     // xc0 = half * 47
    const int y = b >> 2;              // 0..93
    const int xc0 = half * 47;

    const float* src = side ? st : x;
    const float* qs  = side ? qsB : qsA;
    u8* dst = (side ? Bq : Aq) + (size_t)(y * HO + xc0) * DD;

    const int t = threadIdx.x;
    if (t < 47 * 9) {
        const int il = t / 9, k = t - il * 9;
        const int kh = k / 3, kw = k - kh * 3;
        const int i = y * HO + xc0 + il;
        const float scale = qs[i];
        const float* sp = src + (y + kh) * WW + (xc0 + il + kw);
        u8* lp = plds + il * DD + k;
#pragma unroll 8
        for (int c = 0; c < CCH; ++c) {
            int qv = (int)rintf(sp[c * (HH * WW)] * scale);
            lp[c * 9] = (u8)qv;
        }
    }
    __syncthreads();
    // coalesced write-out: 47*2304 bytes = 6768 x 16B
    for (int idx = t; idx < 6768; idx += 512) {
        *(i32x4*)(dst + idx * 16) = *(const i32x4*)(plds + idx * 16);
    }
}

// ---- 4: fused i8 GEMM (A * B^T) + per-row scaled argmax (R8 structure) ----
__global__ __launch_bounds__(512, 2) void k_gemm2(const u8* __restrict__ A,
                                                  const u8* __restrict__ Bm,
                                                  const float* __restrict__ colS,
                                                  u64* __restrict__ best) {
    extern __shared__ __align__(16) u8 lds[];  // 128 KiB

    const int t = threadIdx.x;
    const int wid = t >> 6, lane = t & 63;
    const int wr = wid >> 2, wc = wid & 3;
    const int l15 = lane & 15, l4 = lane >> 4;

    // T1: bijective XCD swizzle (m204), nwg = 1225
    const int nwg = NT2 * NT2;
    const int q = nwg >> 3, r = nwg & 7;  // 153, 1
    const int bid = blockIdx.x;
    const int xcd = bid & 7, loc = bid >> 3;
    const int swz = ((xcd < r) ? xcd * (q + 1) : r * (q + 1) + (xcd - r) * q) + loc;
    const int it = swz / NT2, jt = swz % NT2;

    // staging source (pre-swizzled 16B k-group: (c&3)^((c>>3)&3))
    const int gsrc = (t & 3) ^ ((t >> 3) & 3);
    const u8* pA0 = A  + (size_t)(it * BM2 + (t >> 2)) * DD + gsrc * 16;
    const u8* pB0 = Bm + (size_t)(jt * BM2 + (t >> 2)) * DD + gsrc * 16;

    // fragment read offsets (swizzled): phys 16B-group = l4 ^ ((row>>1)&3)
    const int sp16 = (l4 ^ ((l15 >> 1) & 3)) * 16;
    int aoff[8], boff[4];
#pragma unroll
    for (int mi = 0; mi < 8; ++mi)
        aoff[mi] = (wr * 128 + mi * 16 + l15) * 64 + sp16;
#pragma unroll
    for (int ni = 0; ni < 4; ++ni)
        boff[ni] = BBASEB + (wc * 64 + ni * 16 + l15) * 64 + sp16;

    i32x4 acc[8][4];
#pragma unroll
    for (int mi = 0; mi < 8; ++mi)
#pragma unroll
        for (int ni = 0; ni < 4; ++ni)
            acc[mi][ni] = (i32x4){0, 0, 0, 0};

    // prologue: stage slices 0,1,2
#define PSTAGE(S)                                                            \
    do {                                                                     \
        const u8* sa = pA0 + (size_t)(S) * 64;                               \
        const u8* sb = pB0 + (size_t)(S) * 64;                               \
        gload16(sa,          lds + (S) * ASLB + t * 16);                     \
        gload16(sa + 294912, lds + (S) * ASLB + 8192 + t * 16);              \
        gload16(sb,          lds + BBASEB + (S) * ASLB + t * 16);            \
        gload16(sb + 294912, lds + BBASEB + (S) * ASLB + 8192 + t * 16);     \
    } while (0)
    PSTAGE(0); PSTAGE(1); PSTAGE(2);
#undef PSTAGE
    asm volatile("s_waitcnt vmcnt(8)" ::: "memory");  // slice 0 landed
    __builtin_amdgcn_sched_barrier(0);
    __builtin_amdgcn_s_barrier();

    i32x4 af03[4], af47[4], bfr[4];

// SUB-A: 8 ds_reads (bfr + af03) | stage A-half of slice kb+U+3 | 16 MFMA m0-3
#define SUBA(U)                                                              \
    {                                                                        \
        _Pragma("unroll")                                                    \
        for (int ni = 0; ni < 4; ++ni)                                       \
            bfr[ni] = *(const i32x4*)(lds + (U) * ASLB + boff[ni]);          \
        _Pragma("unroll")                                                    \
        for (int mi = 0; mi < 4; ++mi)                                       \
            af03[mi] = *(const i32x4*)(lds + (U) * ASLB + aoff[mi]);         \
        {                                                                    \
            const int ss = (kb + (U) + 3 > NPH - 1) ? (NPH - 1) : (kb + (U) + 3); \
            const u8* sa = pA0 + (size_t)ss * 64;                            \
            u8* da = lds + (((U) + 3) & 3) * ASLB + t * 16;                  \
            gload16(sa,          da);                                        \
            gload16(sa + 294912, da + 8192);                                 \
        }                                                                    \
        __builtin_amdgcn_s_barrier();                                        \
        asm volatile("s_waitcnt lgkmcnt(0)" ::: "memory");                   \
        __builtin_amdgcn_sched_barrier(0);                                   \
        __builtin_amdgcn_s_setprio(1);                                       \
        _Pragma("unroll")                                                    \
        for (int mi = 0; mi < 4; ++mi)                                       \
            _Pragma("unroll")                                                \
            for (int ni = 0; ni < 4; ++ni)                                   \
                acc[mi][ni] = __builtin_amdgcn_mfma_i32_16x16x64_i8(         \
                    af03[mi], bfr[ni], acc[mi][ni], 0, 0, 0);                \
        __builtin_amdgcn_s_setprio(0);                                       \
        __builtin_amdgcn_s_barrier();                                        \
    }

// SUB-B: 4 ds_reads (af47) | stage B-half | vmcnt(8) | 16 MFMA m4-7 (bfr reuse)
#define SUBB(U)                                                              \
    {                                                                        \
        _Pragma("unroll")                                                    \
        for (int mi = 0; mi < 4; ++mi)                                       \
            af47[mi] = *(const i32x4*)(lds + (U) * ASLB + aoff[4 + mi]);     \
        {                                                                    \
            const int ss = (kb + (U) + 3 > NPH - 1) ? (NPH - 1) : (kb + (U) + 3); \
            const u8* sb = pB0 + (size_t)ss * 64;                            \
            u8* db = lds + BBASEB + (((U) + 3) & 3) * ASLB + t * 16;         \
            gload16(sb,          db);                                       \
            gload16(sb + 294912, db + 8192);                                 \
        }                                                                    \
        asm volatile("s_waitcnt vmcnt(8)" ::: "memory");                     \
        __builtin_amdgcn_sched_barrier(0);                                   \
        __builtin_amdgcn_s_barrier();                                        \
        asm volatile("s_waitcnt lgkmcnt(0)" ::: "memory");                   \
        __builtin_amdgcn_sched_barrier(0);                                   \
        __builtin_amdgcn_s_setprio(1);                                       \
        _Pragma("unroll")                                                    \
        for (int mi = 0; mi < 4; ++mi)                                       \
            _Pragma("unroll")                                                \
            for (int ni = 0; ni < 4; ++ni)                                   \
                acc[4 + mi][ni] = __builtin_amdgcn_mfma_i32_16x16x64_i8(     \
                    af47[mi], bfr[ni], acc[4 + mi][ni], 0, 0, 0);            \
        __builtin_amdgcn_s_setprio(0);                                       \
        __builtin_amdgcn_s_barrier();                                        \
    }

    for (int kt = 0; kt < NPH / 4; ++kt) {
        const int kb = kt * 4;
        SUBA(0) SUBB(0)
        SUBA(1) SUBB(1)
        SUBA(2) SUBB(2)
        SUBA(3) SUBB(3)
    }
#undef SUBA
#undef SUBB

    // epilogue: per output row, argmax of (int dot * colS_j) over 256 j's
    const int jbase = jt * BM2 + wc * 64 + l15;
    float cs[4];
#pragma unroll
    for (int ni = 0; ni < 4; ++ni) {
        int j = jbase + ni * 16;
        cs[ni] = colS[j < LL ? j : 0];
    }
#pragma unroll
    for (int mi = 0; mi < 8; ++mi) {
#pragma unroll
        for (int rr = 0; rr < 4; ++rr) {
            float bv = -3.4e38f;
            int bj = 0x7FFFFFFF;
#pragma unroll
            for (int ni = 0; ni < 4; ++ni) {
                int j = jbase + ni * 16;
                float v = (float)acc[mi][ni][rr] * cs[ni];
                if (j < LL && (v > bv || (v == bv && j < bj))) { bv = v; bj = j; }
            }
#pragma unroll
            for (int m = 1; m < 16; m <<= 1) {
                float ov = __shfl_xor(bv, m, 64);
                int oj = __shfl_xor(bj, m, 64);
                if (ov > bv || (ov == bv && oj < bj)) { bv = ov; bj = oj; }
            }
            if (l15 == 0) {
                int i = it * BM2 + wr * 128 + mi * 16 + l4 * 4 + rr;
                if (i < LL) {
                    unsigned u = __float_as_uint(bv);
                    unsigned s = (bv < 0.f) ? ~u : (u | 0x80000000u);
                    u64 packed = ((u64)s << 32) | (unsigned)(~(unsigned)bj);
                    atomicMax(&best[i], packed);
                }
            }
        }
    }
}

// ---- 5: final scalar ----
__global__ __launch_bounds__(256) void k_final(const u64* __restrict__ best,
                                               const float* __restrict__ rnB,
                                               const float* __restrict__ n2B,
                                               const float* __restrict__ win2x,
                                               const float* __restrict__ sAf,
                                               float* __restrict__ out) {
    int i = blockIdx.x * 256 + threadIdx.x;
    float contrib = 0.f;
    if (i < LL) {
        u64 p = best[i];
        unsigned s = (unsigned)(p >> 32);
        unsigned ub = (s & 0x80000000u) ? (s & 0x7FFFFFFFu) : ~s;
        float bv = __uint_as_float(ub);
        int j = (int)(~(unsigned)(p & 0xFFFFFFFFull));
        float dot = (bv * sAf[i]) / rnB[j];
        contrib = win2x[i] + n2B[j] - 2.f * dot;
    }
    float sred = contrib;
#pragma unroll
    for (int o = 32; o > 0; o >>= 1) sred += __shfl_down(sred, o, 64);
    __shared__ float red[4];
    if ((threadIdx.x & 63) == 0) red[threadIdx.x >> 6] = sred;
    __syncthreads();
    if (threadIdx.x == 0) {
        float tot = red[0] + red[1] + red[2] + red[3];
        atomicAdd(out, tot * (1.0f / ((float)DD * (float)LL)));
    }
}

extern "C" void kernel_launch(void* const* d_in, const int* in_sizes, int n_in,
                              void* d_out, int out_size, void* d_ws, size_t ws_size,
                              hipStream_t stream) {
    const float* x  = (const float*)d_in[0];
    const float* st = (const float*)d_in[1];
    char* ws = (char*)d_ws;

    u8* Aq       = (u8*)ws;
    u8* Bq       = (u8*)(ws + OFF_BQ);
    float* rnB   = (float*)(ws + OFF_RNB);
    float* n2B   = (float*)(ws + OFF_N2B);
    float* win2x = (float*)(ws + OFF_W2X);
    float* qsA   = (float*)(ws + OFF_QSA);
    float* qsB   = (float*)(ws + OFF_QSB);
    float* colS  = (float*)(ws + OFF_COLS);
    float* sAf   = (float*)(ws + OFF_SAF);
    float* P2    = (float*)(ws + OFF_P2);
    float* PM    = (float*)(ws + OFF_PM);
    u64* best    = (u64*)(ws + OFF_BEST);
    float* out   = (float*)d_out;

    hipFuncSetAttribute((const void*)k_gemm2,
                        hipFuncAttributeMaxDynamicSharedMemorySize, 131072);
    hipFuncSetAttribute((const void*)k_pack,
                        hipFuncAttributeMaxDynamicSharedMemorySize, 110592);

    hipMemsetAsync(best, 0, (size_t)LL * 8, stream);
    hipMemsetAsync(out, 0, sizeof(float), stream);
    // zero the pad rows (8836..8959) of both quantized panels
    hipMemsetAsync(Aq + (size_t)LL * DD, 0, (size_t)(LPAD - LL) * DD, stream);
    hipMemsetAsync(Bq + (size_t)LL * DD, 0, (size_t)(LPAD - LL) * DD, stream);

    k_chan_stats<<<dim3(72), dim3(256), 0, stream>>>(st, x, P2, PM);
    k_win<<<dim3(35), dim3(256), 0, stream>>>(P2, PM, rnB, n2B, win2x, qsA, qsB, colS, sAf);
    k_pack<<<dim3(HO * 4), dim3(512), 108288, stream>>>(x, st, qsA, qsB, Aq, Bq);
    k_gemm2<<<dim3(NT2 * NT2), dim3(512), 131072, stream>>>(Aq, Bq, colS, best);
    k_final<<<dim3(35), dim3(256), 0, stream>>>(best, rnB, n2B, win2x, sAf, out);
}

// Round 11
// 350.992 us; speedup vs baseline: 1.2096x; 1.1395x over previous
//
#include <hip/hip_runtime.h>

// ---------------- problem constants ----------------
#define CCH   256
#define HH    96
#define WW    96
#define HO    94
#define LL    8836        // 94*94 patches
#define DD    2304        // 256*9 bytes per patch row (i8)
#define LPAD  8960        // 70 * 128 = 35 * 256

// GEMM: 128x256 block tile, 8 waves (2M x 4N), wave tile 64x64, i8 K=64 MFMA.
// K in 36 slices of 64 B/row; LDS ring-3 of (A 8KB + B 16KB) = 72 KiB.
// 2 blocks/CU (the overlap mechanism: co-resident waves fill MFMA pipe).
#define NTI   70          // M tiles (8960/128)
#define NTJ   35          // N tiles (8960/256)
#define NPH   36          // 2304/64
#define SLTB  24576       // bytes per ring slot (A 8192 + B 16384)

typedef unsigned char u8;
typedef unsigned long long u64;

using i32x4 = __attribute__((ext_vector_type(4))) int;

// ---------------- workspace layout (bytes) ----------------
#define OFF_BQ    20643840ull
#define OFF_RNB   41287680ull
#define OFF_N2B   41323520ull
#define OFF_W2X   41359360ull
#define OFF_QSA   41395200ull
#define OFF_QSB   41431040ull
#define OFF_COLS  41466880ull
#define OFF_SAF   41502720ull
#define OFF_P2    41538560ull
#define OFF_PM    41612288ull
#define OFF_BEST  41686016ull

__device__ __forceinline__ void gload16(const void* g, void* l) {
    __builtin_amdgcn_global_load_lds(
        (const __attribute__((address_space(1))) unsigned int*)g,
        (__attribute__((address_space(3))) unsigned int*)l,
        16, 0, 0);
}

// ---- 1: per-pixel channel sum-of-squares and abs-max for both images ----
__global__ __launch_bounds__(256) void k_chan_stats(const float* __restrict__ st,
                                                    const float* __restrict__ x,
                                                    float* __restrict__ P2,
                                                    float* __restrict__ PM) {
    int p = blockIdx.x * 256 + threadIdx.x;
    if (p >= 2 * HH * WW) return;
    const float* img = (p < HH * WW) ? st : x;
    int pp = (p < HH * WW) ? p : p - HH * WW;
    float s = 0.f, m = 0.f;
#pragma unroll 4
    for (int c = 0; c < CCH; ++c) {
        float v = img[c * (HH * WW) + pp];
        s += v * v;
        m = fmaxf(m, fabsf(v));
    }
    P2[p] = s;
    PM[p] = m;
}

// ---- 2: 3x3 window reductions -> norms, quantizer scales; init best/out ----
__global__ __launch_bounds__(256) void k_win(const float* __restrict__ P2,
                                             const float* __restrict__ PM,
                                             float* __restrict__ rnB,
                                             float* __restrict__ n2B,
                                             float* __restrict__ win2x,
                                             float* __restrict__ qsA,
                                             float* __restrict__ qsB,
                                             float* __restrict__ colS,
                                             float* __restrict__ sAf,
                                             u64* __restrict__ best,
                                             float* __restrict__ out) {
    int i = blockIdx.x * 256 + threadIdx.x;
    if (i >= LL) return;
    if (i == 0) *out = 0.f;
    best[i] = 0;
    int y = i / HO, xc = i % HO;
    float ss = 0.f, sx = 0.f, ms = 0.f, mx = 0.f;
#pragma unroll
    for (int kh = 0; kh < 3; ++kh)
#pragma unroll
        for (int kw = 0; kw < 3; ++kw) {
            int off = (y + kh) * WW + xc + kw;
            ss += P2[off];
            sx += P2[HH * WW + off];
            ms = fmaxf(ms, PM[off]);
            mx = fmaxf(mx, PM[HH * WW + off]);
        }
    float rn = 1.f / (sqrtf(ss) + 1e-8f);
    float msc = fmaxf(ms, 1e-30f), mxc = fmaxf(mx, 1e-30f);
    rnB[i] = rn;
    n2B[i] = ss;
    win2x[i] = sx;
    qsA[i] = 127.f / mxc;
    qsB[i] = 127.f / msc;
    colS[i] = rn * msc * (1.f / 127.f);
    sAf[i] = mxc * (1.f / 127.f);
}

// ---- 3: quantize patches to i8, LDS-transposed for coalesced output ----
__global__ __launch_bounds__(512) void k_pack(const float* __restrict__ x,
                                              const float* __restrict__ st,
                                              const float* __restrict__ qsA,
                                              const float* __restrict__ qsB,
                                              u8* __restrict__ Aq,
                                              u8* __restrict__ Bq) {
    extern __shared__ u8 plds[];   // 47 * 2304 = 108288 bytes

    const int b = blockIdx.x;
    const int side = b & 1;            // 0 = A (x), 1 = B (style)
    const int half = (b >> 1) & 1;     // xc0 = half * 47
    const int y = b >> 2;              // 0..93
    const int xc0 = half * 47;

    const float* src = side ? st : x;
    const float* qs  = side ? qsB : qsA;
    u8* dst = (side ? Bq : Aq) + (size_t)(y * HO + xc0) * DD;

    const int t = threadIdx.x;
    if (t < 47 * 9) {
        const int il = t / 9, k = t - il * 9;
        const int kh = k / 3, kw = k - kh * 3;
        const int i = y * HO + xc0 + il;
        const float scale = qs[i];
        const float* sp = src + (y + kh) * WW + (xc0 + il + kw);
        u8* lp = plds + il * DD + k;
#pragma unroll 8
        for (int c = 0; c < CCH; ++c) {
            int qv = (int)rintf(sp[c * (HH * WW)] * scale);
            lp[c * 9] = (u8)qv;
        }
    }
    __syncthreads();
    for (int idx = t; idx < 6768; idx += 512) {
        *(i32x4*)(dst + idx * 16) = *(const i32x4*)(plds + idx * 16);
    }
}

// ---- 4: fused i8 GEMM (A * B^T) + per-row scaled argmax, 2 blocks/CU ----
__global__ __launch_bounds__(512, 4) void k_gemm2(const u8* __restrict__ A,
                                                  const u8* __restrict__ Bm,
                                                  const float* __restrict__ colS,
                                                  u64* __restrict__ best) {
    extern __shared__ __align__(16) u8 lds[];  // 3 x 24576 = 73728 B

    const int t = threadIdx.x;
    const int wid = t >> 6, lane = t & 63;
    const int wr = wid >> 2, wc = wid & 3;
    const int l15 = lane & 15, l4 = lane >> 4;

    // T1: bijective XCD swizzle (m204), nwg = 2450 (q=306, r=2)
    const int nwg = NTI * NTJ;
    const int q = nwg >> 3, r = nwg & 7;
    const int bid = blockIdx.x;
    const int xcd = bid & 7, loc = bid >> 3;
    const int swz = ((xcd < r) ? xcd * (q + 1) : r * (q + 1) + (xcd - r) * q) + loc;
    const int it = swz / NTJ, jt = swz % NTJ;

    // staging sources (pre-swizzled 16B k-group: (t&3)^((t>>3)&3))
    const int gsrc = (t & 3) ^ ((t >> 3) & 3);
    const u8* srcA = A  + (size_t)(it * 128 + (t >> 2)) * DD + gsrc * 16;
    const u8* srcB = Bm + (size_t)(jt * 256 + (t >> 2)) * DD + gsrc * 16;

    // fragment read offsets (swizzled): phys 16B-group = l4 ^ ((row>>1)&3)
    const int sp16 = (l4 ^ ((l15 >> 1) & 3)) * 16;
    int aoff[4], boff[4];
#pragma unroll
    for (int mi = 0; mi < 4; ++mi)
        aoff[mi] = (wr * 64 + mi * 16 + l15) * 64 + sp16;
#pragma unroll
    for (int ni = 0; ni < 4; ++ni)
        boff[ni] = 8192 + (wc * 64 + ni * 16 + l15) * 64 + sp16;

    i32x4 acc[4][4];
#pragma unroll
    for (int mi = 0; mi < 4; ++mi)
#pragma unroll
        for (int ni = 0; ni < 4; ++ni)
            acc[mi][ni] = (i32x4){0, 0, 0, 0};

    i32x4 af[4], bf[4];

#define STAGE(SS, SP)                                                        \
    do {                                                                     \
        const int sc_ = ((SS) > NPH - 1) ? (NPH - 1) : (SS);                 \
        const u8* sa = srcA + (size_t)sc_ * 64;                              \
        const u8* sb = srcB + (size_t)sc_ * 64;                              \
        u8* d = lds + (SP) * SLTB + t * 16;                                  \
        gload16(sa, d);                                                      \
        gload16(sb, d + 8192);                                               \
        gload16(sb + 128 * DD, d + 16384);                                   \
    } while (0)

    // prologue: stage slices 0,1
    STAGE(0, 0);
    STAGE(1, 1);
    asm volatile("s_waitcnt vmcnt(3)" ::: "memory");  // slice 0 landed
    __builtin_amdgcn_sched_barrier(0);
    __builtin_amdgcn_s_barrier();

// BODY(S): consume slot SC (slice S), stage slice S+2 into slot SP.
#define BODY(S, SC, SP)                                                      \
    {                                                                        \
        _Pragma("unroll")                                                    \
        for (int ni = 0; ni < 4; ++ni)                                       \
            bf[ni] = *(const i32x4*)(lds + (SC) * SLTB + boff[ni]);          \
        _Pragma("unroll")                                                    \
        for (int mi = 0; mi < 4; ++mi)                                       \
            af[mi] = *(const i32x4*)(lds + (SC) * SLTB + aoff[mi]);          \
        STAGE((S) + 2, SP);                                                  \
        asm volatile("s_waitcnt vmcnt(3)" ::: "memory");                     \
        __builtin_amdgcn_sched_barrier(0);                                   \
        __builtin_amdgcn_s_barrier();                                        \
        asm volatile("s_waitcnt lgkmcnt(0)" ::: "memory");                   \
        __builtin_amdgcn_sched_barrier(0);                                   \
        __builtin_amdgcn_s_setprio(1);                                       \
        _Pragma("unroll")                                                    \
        for (int mi = 0; mi < 4; ++mi)                                       \
            _Pragma("unroll")                                                \
            for (int ni = 0; ni < 4; ++ni)                                   \
                acc[mi][ni] = __builtin_amdgcn_mfma_i32_16x16x64_i8(         \
                    af[mi], bf[ni], acc[mi][ni], 0, 0, 0);                   \
        __builtin_amdgcn_s_setprio(0);                                       \
        __builtin_amdgcn_s_barrier();                                        \
    }

    for (int s3 = 0; s3 < NPH; s3 += 3) {
        BODY(s3,     0, 2)
        BODY(s3 + 1, 1, 0)
        BODY(s3 + 2, 2, 1)
    }
#undef BODY
#undef STAGE

    // epilogue: per output row, argmax of (int dot * colS_j) over 256 j's
    const int jbase = jt * 256 + wc * 64 + l15;
    float cs[4];
#pragma unroll
    for (int ni = 0; ni < 4; ++ni) {
        int j = jbase + ni * 16;
        cs[ni] = colS[j < LL ? j : 0];
    }
#pragma unroll
    for (int mi = 0; mi < 4; ++mi) {
#pragma unroll
        for (int rr = 0; rr < 4; ++rr) {
            float bv = -3.4e38f;
            int bj = 0x7FFFFFFF;
#pragma unroll
            for (int ni = 0; ni < 4; ++ni) {
                int j = jbase + ni * 16;
                float v = (float)acc[mi][ni][rr] * cs[ni];
                if (j < LL && (v > bv || (v == bv && j < bj))) { bv = v; bj = j; }
            }
#pragma unroll
            for (int m = 1; m < 16; m <<= 1) {
                float ov = __shfl_xor(bv, m, 64);
                int oj = __shfl_xor(bj, m, 64);
                if (ov > bv || (ov == bv && oj < bj)) { bv = ov; bj = oj; }
            }
            if (l15 == 0) {
                int i = it * 128 + wr * 64 + mi * 16 + l4 * 4 + rr;
                if (i < LL) {
                    unsigned u = __float_as_uint(bv);
                    unsigned s = (bv < 0.f) ? ~u : (u | 0x80000000u);
                    u64 packed = ((u64)s << 32) | (unsigned)(~(unsigned)bj);
                    atomicMax(&best[i], packed);
                }
            }
        }
    }
}

// ---- 5: final scalar ----
__global__ __launch_bounds__(256) void k_final(const u64* __restrict__ best,
                                               const float* __restrict__ rnB,
                                               const float* __restrict__ n2B,
                                               const float* __restrict__ win2x,
                                               const float* __restrict__ sAf,
                                               float* __restrict__ out) {
    int i = blockIdx.x * 256 + threadIdx.x;
    float contrib = 0.f;
    if (i < LL) {
        u64 p = best[i];
        unsigned s = (unsigned)(p >> 32);
        unsigned ub = (s & 0x80000000u) ? (s & 0x7FFFFFFFu) : ~s;
        float bv = __uint_as_float(ub);
        int j = (int)(~(unsigned)(p & 0xFFFFFFFFull));
        float dot = (bv * sAf[i]) / rnB[j];
        contrib = win2x[i] + n2B[j] - 2.f * dot;
    }
    float sred = contrib;
#pragma unroll
    for (int o = 32; o > 0; o >>= 1) sred += __shfl_down(sred, o, 64);
    __shared__ float red[4];
    if ((threadIdx.x & 63) == 0) red[threadIdx.x >> 6] = sred;
    __syncthreads();
    if (threadIdx.x == 0) {
        float tot = red[0] + red[1] + red[2] + red[3];
        atomicAdd(out, tot * (1.0f / ((float)DD * (float)LL)));
    }
}

extern "C" void kernel_launch(void* const* d_in, const int* in_sizes, int n_in,
                              void* d_out, int out_size, void* d_ws, size_t ws_size,
                              hipStream_t stream) {
    const float* x  = (const float*)d_in[0];
    const float* st = (const float*)d_in[1];
    char* ws = (char*)d_ws;

    u8* Aq       = (u8*)ws;
    u8* Bq       = (u8*)(ws + OFF_BQ);
    float* rnB   = (float*)(ws + OFF_RNB);
    float* n2B   = (float*)(ws + OFF_N2B);
    float* win2x = (float*)(ws + OFF_W2X);
    float* qsA   = (float*)(ws + OFF_QSA);
    float* qsB   = (float*)(ws + OFF_QSB);
    float* colS  = (float*)(ws + OFF_COLS);
    float* sAf   = (float*)(ws + OFF_SAF);
    float* P2    = (float*)(ws + OFF_P2);
    float* PM    = (float*)(ws + OFF_PM);
    u64* best    = (u64*)(ws + OFF_BEST);
    float* out   = (float*)d_out;

    hipFuncSetAttribute((const void*)k_gemm2,
                        hipFuncAttributeMaxDynamicSharedMemorySize, 73728);
    hipFuncSetAttribute((const void*)k_pack,
                        hipFuncAttributeMaxDynamicSharedMemorySize, 110592);

    k_chan_stats<<<dim3(72), dim3(256), 0, stream>>>(st, x, P2, PM);
    k_win<<<dim3(35), dim3(256), 0, stream>>>(P2, PM, rnB, n2B, win2x,
                                              qsA, qsB, colS, sAf, best, out);
    k_pack<<<dim3(HO * 4), dim3(512), 108288, stream>>>(x, st, qsA, qsB, Aq, Bq);
    k_gemm2<<<dim3(NTI * NTJ), dim3(512), 73728, stream>>>(Aq, Bq, colS, best);
    k_final<<<dim3(35), dim3(256), 0, stream>>>(best, rnB, n2B, win2x, sAf, out);
}